// Round 5
// baseline (439.380 us; speedup 1.0000x reference)
//
#include <hip/hip_runtime.h>

#define S_LEN 2048

typedef __attribute__((ext_vector_type(8))) short bf16x8;
typedef __attribute__((ext_vector_type(4))) float f32x4;
typedef unsigned long long u64;
typedef unsigned int u32;
typedef unsigned short u16;

#define MFMA16 __builtin_amdgcn_mfma_f32_16x16x32_bf16
#define LN2F 0.69314718056f
#define QSCALE 0.18033688011f   /* 0.125 * log2(e) */

__device__ __forceinline__ u32 asu(float f) { union { float f; u32 u; } v; v.f = f; return v.u; }

// pack 2 floats -> bf16 pair (a=low16, b=high16), round-half-up via +0x8000 + v_perm.
__device__ __forceinline__ u32 pkbf(float a, float b) {
  return __builtin_amdgcn_perm(asu(b) + 0x8000u, asu(a) + 0x8000u, 0x07060302u);
}

// 64x64 bf16 tile, 128B rows, 8 x 16B blocks/row, block swizzled by xor(row&7).
__device__ __forceinline__ u64* qkaddr(u16* dst, int row, int c4) {
  const int cb = c4 >> 1;
  return (u64*)((char*)dst + ((((row << 3) + (cb ^ (row & 7))) << 4) + ((c4 & 1) << 3)));
}
__device__ __forceinline__ bf16x8 ldfrag(const u16* base, int row, int blk) {
  const char* p = (const char*)base + (((row << 3) + (blk ^ (row & 7))) << 4);
  return *(const bf16x8*)p;
}
// padded tile: 144B row stride; 16B-aligned rows (b128-safe).
__device__ __forceinline__ bf16x8 ldpad(const u16* base, int row, int blk) {
  const char* p = (const char*)base + row * 144 + (blk << 4);
  return *(const bf16x8*)p;
}

// One block = one (b*h, 64-row q-tile); 2048 blocks, 256 threads (4 waves).
// Single pass over K:  out = ln2*A2 + (1e9 - lse)*Bm - 1e9*Vsum
//   A2 = sum_k mask*(s*log2e)*v   (Q pre-scaled by 0.125*log2e)
//   Bm = sum_k mask*v             (mask as exact bf16 0/1)
//   Vsum[d] = sum_k v[k][d]       (fp32, accumulated during V staging)
//   lse = ln2 * log2 sum_k exp2(s*log2e)   (fixed max 0; |s|<~8)
__global__ __launch_bounds__(256, 4) void attn_kernel(
    const float* __restrict__ gq, const float* __restrict__ gk,
    const float* __restrict__ gv, const int* __restrict__ gmask,
    float* __restrict__ gout) {
  __shared__ __align__(16) u16 sK[64 * 64];        // 8 KB, swizzled
  __shared__ __align__(16) u16 sV[64 * 72];        // 9 KB, V^T (d-major), 144B rows
  __shared__ __align__(16) u16 sW[2 * 64 * 72];    // 18 KB: W1, W2; Q staged here once

  const int t = threadIdx.x;
  const int wv = t >> 6;
  const int lane = t & 63;
  const int c = lane & 15;
  const int quad = lane >> 4;
  const int r0 = t >> 4, c4 = t & 15;

  const int bx = blockIdx.x;
  const int bh = bx & 63;
  const int q0 = (bx >> 6) << 6;

  const float* qg = gq + ((size_t)bh << 17) + ((size_t)q0 << 6);
  const float* kg = gk + ((size_t)bh << 17);
  const float* vg = gv + ((size_t)bh << 17);

  // ---- stage Q once (scaled by 0.125*log2e) into sW region, swizzled ----
  u16* sQs = sW;
#pragma unroll
  for (int i = 0; i < 4; ++i) {
    const int row = r0 + (i << 4);
    const float4 f = *(const float4*)(qg + ((size_t)row << 6) + (c4 << 2));
    const u32 lo = pkbf(f.x * QSCALE, f.y * QSCALE);
    const u32 hi = pkbf(f.z * QSCALE, f.w * QSCALE);
    *qkaddr(sQs, row, c4) = (u64)lo | ((u64)hi << 32);
  }
  __syncthreads();
  // Q fragments register-resident (wave's own 16 q): qf[ks]
  bf16x8 qf[2];
#pragma unroll
  for (int ks = 0; ks < 2; ++ks)
    qf[ks] = ldfrag(sQs, (wv << 4) + c, (ks << 2) + quad);

  f32x4 accA[4], accB[4];
#pragma unroll
  for (int mt = 0; mt < 4; ++mt) {
    f32x4 z = {0.f, 0.f, 0.f, 0.f};
    accA[mt] = z; accB[mt] = z;
  }
  float vs[4] = {0.f, 0.f, 0.f, 0.f};
  float lacc = 0.f;

  u16* sW1 = sW;
  u16* sW2 = sW + 64 * 72;
  const int* mrow = gmask + (size_t)(q0 + (wv << 4) + c) * S_LEN + (quad << 2);

  for (int kt = 0; kt < 32; ++kt) {
    const int k0 = kt << 6;
    // ---- mask loads for THIS tile, issued first (latency hides behind staging+QK) ----
    int4 mm[4];
#pragma unroll
    for (int tr = 0; tr < 4; ++tr)
      mm[tr] = *(const int4*)(mrow + k0 + (tr << 4));
    // ---- stage K (swizzled; quarter-wave conflict-free) ----
#pragma unroll
    for (int i = 0; i < 4; ++i) {
      const int row = r0 + (i << 4);
      const float4 f = *(const float4*)(kg + ((size_t)(k0 + row) << 6) + (c4 << 2));
      const u32 lo = pkbf(f.x, f.y);
      const u32 hi = pkbf(f.z, f.w);
      *qkaddr(sK, row, c4) = (u64)lo | ((u64)hi << 32);
    }
    // ---- stage V^T + fp32 Vsum partials ----
    // lane (r0,c4) owns d = c4+16j (stride-1 in lane) -> LDS bank 4c4+2r0: <=2-way
    // (the old d=4c4+j mapping was a 16-way quarter-wave conflict: the R4 5e7 counter)
#pragma unroll
    for (int j = 0; j < 4; ++j) {
      const int d = c4 + (j << 4);
      const float* vp = vg + ((size_t)(k0 + (r0 << 2)) << 6) + d;
      const float v0 = vp[0], v1 = vp[64], v2 = vp[128], v3 = vp[192];
      vs[j] += (v0 + v1) + (v2 + v3);
      const u64 pk = (u64)pkbf(v0, v1) | ((u64)pkbf(v2, v3) << 32);
      *(u64*)((char*)sV + d * 144 + (r0 << 3)) = pk;
    }
    __syncthreads();
    // ---- QK (S^T = K*Q^T, log2-scaled) + exp2 + W1/W2 formation ----
#pragma unroll
    for (int tr = 0; tr < 4; ++tr) {
      f32x4 acc = {0.f, 0.f, 0.f, 0.f};
      acc = MFMA16(ldfrag(sK, (tr << 4) + c, quad), qf[0], acc, 0, 0, 0);
      acc = MFMA16(ldfrag(sK, (tr << 4) + c, 4 + quad), qf[1], acc, 0, 0, 0);
      // lane holds (s*log2e)[k = k0+16tr+4quad+r][q = q0+16wv+c], r=0..3
      lacc += (__builtin_amdgcn_exp2f(acc[0]) + __builtin_amdgcn_exp2f(acc[1])) +
              (__builtin_amdgcn_exp2f(acc[2]) + __builtin_amdgcn_exp2f(acc[3]));
      const float w0 = mm[tr].x ? acc[0] : 0.f;
      const float w1 = mm[tr].y ? acc[1] : 0.f;
      const float w2 = mm[tr].z ? acc[2] : 0.f;
      const float w3 = mm[tr].w ? acc[3] : 0.f;
      const u64 p1 = (u64)pkbf(w0, w1) | ((u64)pkbf(w2, w3) << 32);
      const u32 m_lo = (mm[tr].x ? 0x3F80u : 0u) | (mm[tr].y ? 0x3F800000u : 0u);
      const u32 m_hi = (mm[tr].z ? 0x3F80u : 0u) | (mm[tr].w ? 0x3F800000u : 0u);
      const int off = ((wv << 4) + c) * 144 + (tr << 5) + (quad << 3);
      *(u64*)((char*)sW1 + off) = p1;
      *(u64*)((char*)sW2 + off) = (u64)m_lo | ((u64)m_hi << 32);
    }
    // ---- PV: A2^T += V^T*W1^T ; Bm^T += V^T*W2^T (wave-private W -> no barrier) ----
#pragma unroll
    for (int ks = 0; ks < 2; ++ks) {
      const bf16x8 bw1 = ldpad(sW1, (wv << 4) + c, (ks << 2) + quad);
      const bf16x8 bw2 = ldpad(sW2, (wv << 4) + c, (ks << 2) + quad);
#pragma unroll
      for (int mt = 0; mt < 4; ++mt) {
        const bf16x8 av = ldpad(sV, (mt << 4) + c, (ks << 2) + quad);
        accA[mt] = MFMA16(av, bw1, accA[mt], 0, 0, 0);
        accB[mt] = MFMA16(av, bw2, accB[mt], 0, 0, 0);
      }
    }
    __syncthreads();
  }

  // ---- Vsum reduction (reuse sK as fp32 scratch) ----
  float* sRed = (float*)sK;          // 16 x 64 partials
  float* vsum = (float*)sK + 1024;   // 64 totals
#pragma unroll
  for (int j = 0; j < 4; ++j)
    sRed[(r0 << 6) + c4 + (j << 4)] = vs[j];
  __syncthreads();
  if (t < 64) {
    float s = 0.f;
#pragma unroll
    for (int r = 0; r < 16; ++r) s += sRed[(r << 6) + t];
    vsum[t] = s;
  }
  __syncthreads();

  // ---- lse (wave-local) ----
  float l = lacc;
  l += __shfl_xor(l, 16, 64);
  l += __shfl_xor(l, 32, 64);
  l = LN2F * __builtin_amdgcn_logf(l);   // ln(sum) from log2
  const float c1 = 1e9f - l;

  // ---- epilogue: out[b][q][h*64+d] = ln2*A2 + c1*Bm - 1e9*Vsum ----
  const int b = bh >> 4, h = bh & 15;
  const int qrow = q0 + (wv << 4) + c;
#pragma unroll
  for (int mt = 0; mt < 4; ++mt) {
    const f32x4 v4 = *(const f32x4*)(vsum + (mt << 4) + (quad << 2));
    float4 o;
    o.x = LN2F * accA[mt][0] + c1 * accB[mt][0] - 1e9f * v4[0];
    o.y = LN2F * accA[mt][1] + c1 * accB[mt][1] - 1e9f * v4[1];
    o.z = LN2F * accA[mt][2] + c1 * accB[mt][2] - 1e9f * v4[2];
    o.w = LN2F * accA[mt][3] + c1 * accB[mt][3] - 1e9f * v4[3];
    const size_t off = ((size_t)b * S_LEN + (size_t)qrow) * 1024 +
                       (h << 6) + (mt << 4) + (quad << 2);
    *(float4*)(gout + off) = o;
  }
}

extern "C" void kernel_launch(void* const* d_in, const int* in_sizes, int n_in,
                              void* d_out, int out_size, void* d_ws, size_t ws_size,
                              hipStream_t stream) {
  const float* q = (const float*)d_in[0];
  const float* k = (const float*)d_in[1];
  const float* v = (const float*)d_in[2];
  const int* mask = (const int*)d_in[3];
  (void)in_sizes; (void)n_in; (void)out_size; (void)d_ws; (void)ws_size;
  attn_kernel<<<dim3(2048), dim3(256), 0, stream>>>(q, k, v, mask, (float*)d_out);
}